// Round 5
// baseline (116.414 us; speedup 1.0000x reference)
//
#include <hip/hip_runtime.h>
#include <hip/hip_bf16.h>

#define N 512
#define D 256
#define MARGIN 0.1f
#define EPSF 1e-16f
#define PAD 4
#define NBLK 256
#define AGENT __HIP_MEMORY_SCOPE_AGENT

union SharedU {
    struct {
        float As[32][D + PAD];
        float Bs[32][D + PAD];
        float norms[64];
    } p1;
    struct {
        float row[2][N];
        unsigned long long masks[8];
        short plist[N];
    } p2;
};

__global__ __launch_bounds__(256) void fused_kernel(const float* __restrict__ E,
                                                    const int* __restrict__ labels,
                                                    float* __restrict__ pd,
                                                    float* __restrict__ bsum,
                                                    float* __restrict__ bcnt,
                                                    unsigned int* __restrict__ cnts,
                                                    float* __restrict__ out) {
    __shared__ SharedU sh;
    __shared__ int   lab[N];
    __shared__ float rsum[256];
    __shared__ int   rcnt[256];
    __shared__ double fs[256];
    __shared__ double fc[256];
    __shared__ unsigned int ticket_s;

    int t   = threadIdx.x;
    int blk = blockIdx.x;

    // ================= Phase 1: pd tile (32x32) + fused norms =================
    {
        int bi = blk >> 4, bj = blk & 15;

        lab[t]       = labels[t];
        lab[t + 256] = labels[t + 256];

        const float4* E4 = (const float4*)E;  // row = 64 float4
        #pragma unroll
        for (int it = 0; it < 8; ++it) {
            int idx = it * 256 + t;
            int r = idx >> 6;
            int c = idx & 63;
            float4 va = E4[(bi * 32 + r) * 64 + c];
            *(float4*)&sh.p1.As[r][c * 4] = va;
            float4 vb = E4[(bj * 32 + r) * 64 + c];
            *(float4*)&sh.p1.Bs[r][c * 4] = vb;
        }
        __syncthreads();

        // fused squared-norms: 4 threads per staged row
        {
            int r  = t >> 2;
            int ch = t & 3;
            const float* src = (r < 32) ? &sh.p1.As[r][0] : &sh.p1.Bs[r - 32][0];
            float np = 0.0f;
            #pragma unroll
            for (int d = 0; d < 64; d += 4) {
                float4 x = *(const float4*)&src[ch * 64 + d];
                np += x.x * x.x + x.y * x.y + x.z * x.z + x.w * x.w;
            }
            np += __shfl_xor(np, 1);
            np += __shfl_xor(np, 2);
            if (ch == 0) sh.p1.norms[r] = np;
        }
        __syncthreads();

        int ri = t >> 4;
        int cj = t & 15;
        float a00 = 0.f, a01 = 0.f, a10 = 0.f, a11 = 0.f;
        for (int d = 0; d < D; d += 4) {
            float4 x0 = *(const float4*)&sh.p1.As[ri][d];
            float4 x1 = *(const float4*)&sh.p1.As[ri + 16][d];
            float4 y0 = *(const float4*)&sh.p1.Bs[cj][d];
            float4 y1 = *(const float4*)&sh.p1.Bs[cj + 16][d];
            a00 += x0.x * y0.x + x0.y * y0.y + x0.z * y0.z + x0.w * y0.w;
            a01 += x0.x * y1.x + x0.y * y1.y + x0.z * y1.z + x0.w * y1.w;
            a10 += x1.x * y0.x + x1.y * y0.y + x1.z * y0.z + x1.w * y0.w;
            a11 += x1.x * y1.x + x1.y * y1.y + x1.z * y1.z + x1.w * y1.w;
        }

        int gi0 = bi * 32 + ri, gi1 = gi0 + 16;
        int gj0 = bj * 32 + cj, gj1 = gj0 + 16;
        float si0 = sh.p1.norms[ri],      si1 = sh.p1.norms[ri + 16];
        float sj0 = sh.p1.norms[32 + cj], sj1 = sh.p1.norms[32 + cj + 16];

        float d00 = fmaxf(si0 - 2.0f * a00 + sj0, 0.0f);
        float d01 = fmaxf(si0 - 2.0f * a01 + sj1, 0.0f);
        float d10 = fmaxf(si1 - 2.0f * a10 + sj0, 0.0f);
        float d11 = fmaxf(si1 - 2.0f * a11 + sj1, 0.0f);
        pd[gi0 * N + gj0] = (d00 > 0.0f) ? sqrtf(d00) : 0.0f;
        pd[gi0 * N + gj1] = (d01 > 0.0f) ? sqrtf(d01) : 0.0f;
        pd[gi1 * N + gj0] = (d10 > 0.0f) ? sqrtf(d10) : 0.0f;
        pd[gi1 * N + gj1] = (d11 > 0.0f) ? sqrtf(d11) : 0.0f;
    }

    // ================= Hand-rolled grid barrier ==============================
    __threadfence();      // release: write back dirty pd lines (agent scope)
    __syncthreads();
    if (t == 0) {
        __hip_atomic_fetch_add(&cnts[0], 1u, __ATOMIC_ACQ_REL, AGENT);
        while (__hip_atomic_load(&cnts[0], __ATOMIC_ACQUIRE, AGENT) < NBLK) {
            __builtin_amdgcn_s_sleep(1);
        }
    }
    __syncthreads();
    __threadfence();      // acquire: invalidate stale cross-XCD L2 lines

    // ================= Phase 2: two anchors per block ========================
    int i0 = blk, i1 = blk + 256;
    sh.p2.row[0][t]       = pd[i0 * N + t];
    sh.p2.row[0][t + 256] = pd[i0 * N + t + 256];
    sh.p2.row[1][t]       = pd[i1 * N + t];
    sh.p2.row[1][t + 256] = pd[i1 * N + t + 256];
    __syncthreads();

    int wave = t >> 6;
    int lane = t & 63;
    unsigned long long lower = (1ULL << lane) - 1ULL;

    float sum = 0.0f;
    int   cnt = 0;
    for (int a = 0; a < 2; ++a) {
        int i = (a == 0) ? i0 : i1;
        const float* row = sh.p2.row[a];

        int li = lab[i];
        int j1 = t, j2 = t + 256;
        bool pp1 = (lab[j1] == li) && (j1 != i);
        bool pp2 = (lab[j2] == li) && (j2 != i);
        unsigned long long m1 = __ballot(pp1);
        unsigned long long m2 = __ballot(pp2);
        if (lane == 0) { sh.p2.masks[wave] = m1; sh.p2.masks[wave + 4] = m2; }
        __syncthreads();

        int base1 = 0, base2 = 0, npos = 0;
        #pragma unroll
        for (int c = 0; c < 8; ++c) {
            int pc = __popcll(sh.p2.masks[c]);
            if (c < wave)     base1 += pc;
            if (c < wave + 4) base2 += pc;
            npos += pc;
        }
        if (pp1) sh.p2.plist[base1 + __popcll(m1 & lower)] = (short)j1;
        if (pp2) sh.p2.plist[base2 + __popcll(m2 & lower)] = (short)j2;
        __syncthreads();

        bool  n1  = (lab[j1] != li);
        bool  n2  = (lab[j2] != li);
        float dn1 = row[j1];
        float dn2 = row[j2];

        for (int p = 0; p < npos; ++p) {
            float dap = row[sh.p2.plist[p]];
            float v1 = dap - dn1 + MARGIN;
            float v2 = dap - dn2 + MARGIN;
            if (n1 && v1 > 0.0f) { sum += v1; cnt += (v1 > EPSF); }
            if (n2 && v2 > 0.0f) { sum += v2; cnt += (v2 > EPSF); }
        }
        __syncthreads();   // before next anchor overwrites masks/plist
    }

    rsum[t] = sum;
    rcnt[t] = cnt;
    __syncthreads();
    #pragma unroll
    for (int s = 128; s > 0; s >>= 1) {
        if (t < s) {
            rsum[t] += rsum[t + s];
            rcnt[t] += rcnt[t + s];
        }
        __syncthreads();
    }
    if (t == 0) {
        bsum[blk] = rsum[0];
        bcnt[blk] = (float)rcnt[0];
    }

    // ================= Phase 3: ticketed final reduce ========================
    __threadfence();      // release bsum/bcnt
    if (t == 0) {
        ticket_s = __hip_atomic_fetch_add(&cnts[1], 1u, __ATOMIC_ACQ_REL, AGENT);
    }
    __syncthreads();
    if (ticket_s == NBLK - 1) {
        __threadfence();  // acquire: see all blocks' partials
        fs[t] = (double)__hip_atomic_load(&bsum[t], __ATOMIC_RELAXED, AGENT);
        fc[t] = (double)__hip_atomic_load(&bcnt[t], __ATOMIC_RELAXED, AGENT);
        __syncthreads();
        #pragma unroll
        for (int st = 128; st > 0; st >>= 1) {
            if (t < st) {
                fs[t] += fs[t + st];
                fc[t] += fc[t + st];
            }
            __syncthreads();
        }
        if (t == 0) {
            double c = fc[0];
            out[0] = (float)(fs[0] / (c + 1e-16));
            out[1] = (float)c;
        }
    }
}

extern "C" void kernel_launch(void* const* d_in, const int* in_sizes, int n_in,
                              void* d_out, int out_size, void* d_ws, size_t ws_size,
                              hipStream_t stream) {
    const float* E      = (const float*)d_in[0];
    const int*   labels = (const int*)d_in[1];
    float*       out    = (float*)d_out;

    float* pd   = (float*)d_ws;              // 512*512
    float* bsum = pd + N * N;                // 256
    float* bcnt = bsum + 256;                // 256
    unsigned int* cnts = (unsigned int*)(bcnt + 256);   // 2 counters

    hipMemsetAsync(cnts, 0, 2 * sizeof(unsigned int), stream);

    void* args[] = {(void*)&E, (void*)&labels, (void*)&pd,
                    (void*)&bsum, (void*)&bcnt, (void*)&cnts, (void*)&out};
    hipLaunchCooperativeKernel((const void*)fused_kernel,
                               dim3(NBLK), dim3(256), args, 0, stream);
}

// Round 6
// 30.582 us; speedup vs baseline: 3.8067x; 3.8067x over previous
//
#include <hip/hip_runtime.h>
#include <hip/hip_bf16.h>

#define N 512
#define D 256
#define MARGIN 0.1f
#define EPSF 1e-16f
#define NBLK 256
#define AGENT __HIP_MEMORY_SCOPE_AGENT
#define SCALE 268435456.0   /* 2^28 */

__device__ __forceinline__ float fma4(float4 x, float4 a, float acc) {
    acc = fmaf(x.x, a.x, acc);
    acc = fmaf(x.y, a.y, acc);
    acc = fmaf(x.z, a.z, acc);
    acc = fmaf(x.w, a.w, acc);
    return acc;
}

__global__ __launch_bounds__(512) void fused_kernel(const float* __restrict__ E,
                                                    const int* __restrict__ labels,
                                                    unsigned long long* __restrict__ sumAcc,
                                                    unsigned int* __restrict__ cntAcc,
                                                    unsigned int* __restrict__ ticket,
                                                    float* __restrict__ out) {
    __shared__ float dr0[N];
    __shared__ float dr1[N];
    __shared__ float sqv[N];
    __shared__ int   lab[N];
    __shared__ unsigned long long masks[8];
    __shared__ short plist[N];
    __shared__ float rsum[512];
    __shared__ int   rcnt[512];

    int t   = threadIdx.x;
    int blk = blockIdx.x;
    int i0 = blk, i1 = blk + 256;
    int rl = t >> 4;          // 0..31 : row within pass
    int ch = t & 15;          // 0..15 : 16 threads per row

    const float4* E4 = (const float4*)E;   // row = 64 float4

    // Anchor slices in registers: f4 indices {ch, ch+16, ch+32, ch+48}
    float4 a0[4], a1[4];
    #pragma unroll
    for (int k = 0; k < 4; ++k) {
        a0[k] = E4[i0 * 64 + ch + 16 * k];
        a1[k] = E4[i1 * 64 + ch + 16 * k];
    }
    lab[t] = labels[t];

    // ---- Stream E from global (L2-resident), registers only ----
    #pragma unroll 2
    for (int p = 0; p < 16; ++p) {
        int j = p * 32 + rl;
        const float4* base = E4 + j * 64 + ch;
        float4 x0 = base[0];
        float4 x1 = base[16];
        float4 x2 = base[32];
        float4 x3 = base[48];
        float d0 = 0.f, d1 = 0.f, sq = 0.f;
        d0 = fma4(x0, a0[0], d0); d0 = fma4(x1, a0[1], d0);
        d0 = fma4(x2, a0[2], d0); d0 = fma4(x3, a0[3], d0);
        d1 = fma4(x0, a1[0], d1); d1 = fma4(x1, a1[1], d1);
        d1 = fma4(x2, a1[2], d1); d1 = fma4(x3, a1[3], d1);
        sq = fma4(x0, x0, sq);    sq = fma4(x1, x1, sq);
        sq = fma4(x2, x2, sq);    sq = fma4(x3, x3, sq);
        // reduce across the 16 threads of this row (same order for all three)
        #pragma unroll
        for (int m = 1; m <= 8; m <<= 1) {
            d0 += __shfl_xor(d0, m);
            d1 += __shfl_xor(d1, m);
            sq += __shfl_xor(sq, m);
        }
        if (ch == 0) {
            dr0[j] = d0;
            dr1[j] = d1;
            sqv[j] = sq;
        }
    }
    __syncthreads();

    // ---- dots -> distances (in LDS) ----
    {
        float si0 = sqv[i0], si1 = sqv[i1];
        float sj  = sqv[t];
        float dd0 = fmaxf(si0 - 2.0f * dr0[t] + sj, 0.0f);
        float dd1 = fmaxf(si1 - 2.0f * dr1[t] + sj, 0.0f);
        dr0[t] = (dd0 > 0.0f) ? sqrtf(dd0) : 0.0f;
        dr1[t] = (dd1 > 0.0f) ? sqrtf(dd1) : 0.0f;
    }
    __syncthreads();

    // ---- triplet accumulation, 2 anchors, ballot-compacted positives ----
    int wave = t >> 6;
    int lane = t & 63;
    unsigned long long lower = (1ULL << lane) - 1ULL;

    float sum = 0.0f;
    int   cnt = 0;
    for (int a = 0; a < 2; ++a) {
        int i = (a == 0) ? i0 : i1;
        const float* row = (a == 0) ? dr0 : dr1;

        int li = lab[i];
        bool pos = (lab[t] == li) && (t != i);
        unsigned long long m = __ballot(pos);
        if (lane == 0) masks[wave] = m;
        __syncthreads();

        int base = 0, npos = 0;
        #pragma unroll
        for (int c = 0; c < 8; ++c) {
            int pc = __popcll(masks[c]);
            if (c < wave) base += pc;
            npos += pc;
        }
        if (pos) plist[base + __popcll(m & lower)] = (short)t;
        __syncthreads();

        bool  neg = (lab[t] != li);
        float dn  = row[t];
        for (int p = 0; p < npos; ++p) {
            float v = row[plist[p]] - dn + MARGIN;
            if (neg && v > 0.0f) { sum += v; cnt += (v > EPSF); }
        }
        __syncthreads();   // before next anchor overwrites masks/plist
    }

    rsum[t] = sum;
    rcnt[t] = cnt;
    __syncthreads();
    #pragma unroll
    for (int s = 256; s > 0; s >>= 1) {
        if (t < s) {
            rsum[t] += rsum[t + s];
            rcnt[t] += rcnt[t + s];
        }
        __syncthreads();
    }

    // ---- deterministic global accumulation (integer atomics) + ticket ----
    if (t == 0) {
        unsigned long long q =
            (unsigned long long)__double2ll_rn((double)rsum[0] * SCALE);
        atomicAdd(sumAcc, q);
        atomicAdd(cntAcc, (unsigned int)rcnt[0]);
        __threadfence();
        unsigned int tk = atomicAdd(ticket, 1u);
        if (tk == NBLK - 1) {
            __threadfence();
            unsigned long long S = __hip_atomic_load(sumAcc, __ATOMIC_RELAXED, AGENT);
            unsigned int       C = __hip_atomic_load(cntAcc, __ATOMIC_RELAXED, AGENT);
            double sm = (double)S * (1.0 / SCALE);
            out[0] = (float)(sm / ((double)C + 1e-16));
            out[1] = (float)C;
        }
    }
}

extern "C" void kernel_launch(void* const* d_in, const int* in_sizes, int n_in,
                              void* d_out, int out_size, void* d_ws, size_t ws_size,
                              hipStream_t stream) {
    const float* E      = (const float*)d_in[0];
    const int*   labels = (const int*)d_in[1];
    float*       out    = (float*)d_out;

    unsigned long long* sumAcc = (unsigned long long*)d_ws;          // 8 B
    unsigned int*       cntAcc = (unsigned int*)((char*)d_ws + 8);   // 4 B
    unsigned int*       ticket = (unsigned int*)((char*)d_ws + 12);  // 4 B

    hipMemsetAsync(d_ws, 0, 16, stream);
    fused_kernel<<<NBLK, 512, 0, stream>>>(E, labels, sumAcc, cntAcc, ticket, out);
}